// Round 1
// baseline (3903.837 us; speedup 1.0000x reference)
//
#include <hip/hip_runtime.h>

// GIN forward: 4x (scatter-sum over edges + Linear+ReLU), mean-pool per graph, post-MLP.
// Round 1: correctness-first fp32. Scatter via global f32 atomics; GEMM via
// LDS-tiled vector-ALU fp32 (no fp32 MFMA on CDNA4).

#define N_NODES  50000
#define N_EDGES  600000
#define N_FEAT   64
#define DIM      128
#define N_GRAPHS 1024

// ---------------- scatter: agg[dst] += h[src], F features ----------------
template<int F>
__global__ __launch_bounds__(256) void scatter_add_k(
    const float* __restrict__ h, const int* __restrict__ src,
    const int* __restrict__ dst, float* __restrict__ agg) {
  constexpr int C = F / 4;                 // float4 chunks per edge
  int idx = blockIdx.x * 256 + threadIdx.x;
  int e = idx / C;
  int c = (idx % C) * 4;
  if (e >= N_EDGES) return;
  int s = src[e];
  int d = dst[e];
  float4 v = *reinterpret_cast<const float4*>(h + (size_t)s * F + c);
  float* a = agg + (size_t)d * F + c;
  atomicAdd(a + 0, v.x);
  atomicAdd(a + 1, v.y);
  atomicAdd(a + 2, v.z);
  atomicAdd(a + 3, v.w);
}

// ------------- fused GEMM+bias+ReLU: out = relu((x+agg) @ W + b) -------------
// out[M][128], x/agg[M][K], W[K][128]. In-place safe (out==x): each block fully
// stages its 32 rows into LDS before writing them back.
template<int K>
__global__ __launch_bounds__(256) void gemm_relu_k(
    const float* __restrict__ x, const float* __restrict__ agg,
    const float* __restrict__ W, const float* __restrict__ bias,
    float* __restrict__ out, int M) {
  constexpr int N = 128, ROWS = 32, KB = 64;
  __shared__ float Ws[KB][N];      // 32 KB k-tile of W
  __shared__ float xs[ROWS][K];    // 8 or 16 KB of (x+agg) rows
  __shared__ float bs[N];

  int tid = threadIdx.x;
  int row0 = blockIdx.x * ROWS;
  if (tid < N) bs[tid] = bias[tid];

  // stage xs = x + agg (float4, coalesced)
  for (int i = tid; i < ROWS * K / 4; i += 256) {
    int r  = i / (K / 4);
    int kk = (i % (K / 4)) * 4;
    int row = row0 + r;
    float4 s = make_float4(0.f, 0.f, 0.f, 0.f);
    if (row < M) {
      float4 xv = *reinterpret_cast<const float4*>(x   + (size_t)row * K + kk);
      float4 av = *reinterpret_cast<const float4*>(agg + (size_t)row * K + kk);
      s = make_float4(xv.x + av.x, xv.y + av.y, xv.z + av.z, xv.w + av.w);
    }
    *reinterpret_cast<float4*>(&xs[r][kk]) = s;
  }

  int colg = tid & 31;   // owns cols 4*colg .. 4*colg+3
  int rowg = tid >> 5;   // owns rows 4*rowg .. 4*rowg+3

  float acc[4][4];
#pragma unroll
  for (int r = 0; r < 4; ++r)
#pragma unroll
    for (int c = 0; c < 4; ++c) acc[r][c] = 0.f;

  for (int kb = 0; kb < K; kb += KB) {
    __syncthreads();   // xs ready (iter 0); prior compute done before Ws reuse
    for (int i = tid; i < KB * N / 4; i += 256) {
      reinterpret_cast<float4*>(&Ws[0][0])[i] =
          reinterpret_cast<const float4*>(W + (size_t)kb * N)[i];
    }
    __syncthreads();
#pragma unroll 8
    for (int k = 0; k < KB; ++k) {
      float4 w4 = *reinterpret_cast<const float4*>(&Ws[k][colg * 4]);
      float x0 = xs[rowg * 4 + 0][kb + k];
      float x1 = xs[rowg * 4 + 1][kb + k];
      float x2 = xs[rowg * 4 + 2][kb + k];
      float x3 = xs[rowg * 4 + 3][kb + k];
      acc[0][0] = fmaf(x0, w4.x, acc[0][0]); acc[0][1] = fmaf(x0, w4.y, acc[0][1]);
      acc[0][2] = fmaf(x0, w4.z, acc[0][2]); acc[0][3] = fmaf(x0, w4.w, acc[0][3]);
      acc[1][0] = fmaf(x1, w4.x, acc[1][0]); acc[1][1] = fmaf(x1, w4.y, acc[1][1]);
      acc[1][2] = fmaf(x1, w4.z, acc[1][2]); acc[1][3] = fmaf(x1, w4.w, acc[1][3]);
      acc[2][0] = fmaf(x2, w4.x, acc[2][0]); acc[2][1] = fmaf(x2, w4.y, acc[2][1]);
      acc[2][2] = fmaf(x2, w4.z, acc[2][2]); acc[2][3] = fmaf(x2, w4.w, acc[2][3]);
      acc[3][0] = fmaf(x3, w4.x, acc[3][0]); acc[3][1] = fmaf(x3, w4.y, acc[3][1]);
      acc[3][2] = fmaf(x3, w4.z, acc[3][2]); acc[3][3] = fmaf(x3, w4.w, acc[3][3]);
    }
  }

#pragma unroll
  for (int r = 0; r < 4; ++r) {
    int row = row0 + rowg * 4 + r;
    if (row < M) {
      float4 o;
      o.x = fmaxf(acc[r][0] + bs[colg * 4 + 0], 0.f);
      o.y = fmaxf(acc[r][1] + bs[colg * 4 + 1], 0.f);
      o.z = fmaxf(acc[r][2] + bs[colg * 4 + 2], 0.f);
      o.w = fmaxf(acc[r][3] + bs[colg * 4 + 3], 0.f);
      *reinterpret_cast<float4*>(out + (size_t)row * N + colg * 4) = o;
    }
  }
}

// ---------------- per-graph sum + count (atomics) ----------------
__global__ __launch_bounds__(256) void pool_sum_k(
    const float* __restrict__ h, const int* __restrict__ batch,
    float* __restrict__ pooled, float* __restrict__ counts) {
  int idx = blockIdx.x * 256 + threadIdx.x;
  int node = idx >> 5;           // 32 threads per node (128 feats / 4)
  int c = (idx & 31) * 4;
  if (node >= N_NODES) return;
  int g = batch[node];
  float4 v = *reinterpret_cast<const float4*>(h + (size_t)node * DIM + c);
  float* p = pooled + (size_t)g * DIM + c;
  atomicAdd(p + 0, v.x);
  atomicAdd(p + 1, v.y);
  atomicAdd(p + 2, v.z);
  atomicAdd(p + 3, v.w);
  if (c == 0) atomicAdd(counts + g, 1.0f);
}

// ---------------- post-MLP: out = relu((pooled/count) @ Wp + bp) ----------------
__global__ __launch_bounds__(128) void post_mlp_k(
    const float* __restrict__ pooled, const float* __restrict__ counts,
    const float* __restrict__ W, const float* __restrict__ bias,
    float* __restrict__ out) {
  __shared__ float xs[DIM];
  int g = blockIdx.x;
  int col = threadIdx.x;
  float cnt = fmaxf(counts[g], 1.0f);
  xs[col] = pooled[(size_t)g * DIM + col] / cnt;
  __syncthreads();
  float acc = bias[col];
  for (int k = 0; k < DIM; ++k)
    acc = fmaf(xs[k], W[(size_t)k * DIM + col], acc);
  out[(size_t)g * DIM + col] = fmaxf(acc, 0.f);
}

extern "C" void kernel_launch(void* const* d_in, const int* in_sizes, int n_in,
                              void* d_out, int out_size, void* d_ws, size_t ws_size,
                              hipStream_t stream) {
  const float* x    = (const float*)d_in[0];   // 50000 x 64
  const int*   ei   = (const int*)d_in[1];     // 2 x 600000
  const int*   batch= (const int*)d_in[2];     // 50000
  const float* w0 = (const float*)d_in[3];  const float* b0 = (const float*)d_in[4];
  const float* w1 = (const float*)d_in[5];  const float* b1 = (const float*)d_in[6];
  const float* w2 = (const float*)d_in[7];  const float* b2 = (const float*)d_in[8];
  const float* w3 = (const float*)d_in[9];  const float* b3 = (const float*)d_in[10];
  const float* wp = (const float*)d_in[11]; const float* bp = (const float*)d_in[12];
  float* out = (float*)d_out;

  const int* src = ei;
  const int* dst = ei + N_EDGES;

  // workspace layout (all fp32): agg[50000*128] | h[50000*128] | pooled[1024*128] | counts[1024]
  float* agg    = (float*)d_ws;
  float* h      = agg + (size_t)N_NODES * DIM;
  float* pooled = h + (size_t)N_NODES * DIM;
  float* counts = pooled + (size_t)N_GRAPHS * DIM;

  // ---- layer 0: K=64 -> 128 ----
  hipMemsetAsync(agg, 0, (size_t)N_NODES * N_FEAT * sizeof(float), stream);
  {
    int total = N_EDGES * (N_FEAT / 4);
    scatter_add_k<N_FEAT><<<(total + 255) / 256, 256, 0, stream>>>(x, src, dst, agg);
  }
  gemm_relu_k<N_FEAT><<<(N_NODES + 31) / 32, 256, 0, stream>>>(x, agg, w0, b0, h, N_NODES);

  // ---- layers 1..3: K=128 -> 128 (h updated in place) ----
  const float* Wl[3] = {w1, w2, w3};
  const float* Bl[3] = {b1, b2, b3};
  for (int l = 0; l < 3; ++l) {
    hipMemsetAsync(agg, 0, (size_t)N_NODES * DIM * sizeof(float), stream);
    int total = N_EDGES * (DIM / 4);
    scatter_add_k<DIM><<<(total + 255) / 256, 256, 0, stream>>>(h, src, dst, agg);
    gemm_relu_k<DIM><<<(N_NODES + 31) / 32, 256, 0, stream>>>(h, agg, Wl[l], Bl[l], h, N_NODES);
  }

  // ---- mean pool + post MLP ----
  hipMemsetAsync(pooled, 0, ((size_t)N_GRAPHS * DIM + N_GRAPHS) * sizeof(float), stream);
  {
    int total = N_NODES * (DIM / 4);
    pool_sum_k<<<(total + 255) / 256, 256, 0, stream>>>(h, batch, pooled, counts);
  }
  post_mlp_k<<<N_GRAPHS, 128, 0, stream>>>(pooled, counts, wp, bp, out);
}

// Round 2
// 664.603 us; speedup vs baseline: 5.8739x; 5.8739x over previous
//
#include <hip/hip_runtime.h>

// GIN forward, round 2: replace f32-atomic scatter with CSR-by-dst build +
// register-accumulating gather (one wave per node). Atomics remain only in the
// int CSR build (600k) and the small pool (6.4M).

#define N_NODES  50000
#define N_EDGES  600000
#define N_FEAT   64
#define DIM      128
#define N_GRAPHS 1024

// ---------------- CSR build ----------------
__global__ __launch_bounds__(256) void hist_k(
    const int* __restrict__ dst, int* __restrict__ cnt) {
  int e = blockIdx.x * 256 + threadIdx.x;
  if (e < N_EDGES) atomicAdd(&cnt[dst[e]], 1);
}

// single-block exclusive scan over N_NODES counts -> row_ptr (N_NODES+1)
__global__ __launch_bounds__(256) void scan_k(
    const int* __restrict__ cnt, int* __restrict__ row_ptr) {
  __shared__ int sums[256];
  const int T = 256;
  const int chunk = (N_NODES + T - 1) / T;   // 196
  int t = threadIdx.x;
  int base = t * chunk;
  int n = min(chunk, max(0, N_NODES - base));
  int local = 0;
  for (int i = 0; i < n; ++i) local += cnt[base + i];
  sums[t] = local;
  __syncthreads();
  // Hillis-Steele inclusive scan over 256 partials
  for (int off = 1; off < T; off <<= 1) {
    int v = (t >= off) ? sums[t - off] : 0;
    __syncthreads();
    sums[t] += v;
    __syncthreads();
  }
  int run = sums[t] - local;   // exclusive prefix of this thread's chunk
  for (int i = 0; i < n; ++i) {
    row_ptr[base + i] = run;
    run += cnt[base + i];
  }
  if (t == T - 1) row_ptr[N_NODES] = run;
}

__global__ __launch_bounds__(256) void fill_k(
    const int* __restrict__ src, const int* __restrict__ dst,
    const int* __restrict__ row_ptr, int* __restrict__ fill,
    int* __restrict__ csr_src) {
  int e = blockIdx.x * 256 + threadIdx.x;
  if (e >= N_EDGES) return;
  int d = dst[e];
  int pos = row_ptr[d] + atomicAdd(&fill[d], 1);
  csr_src[pos] = src[e];
}

// ---------------- gather aggregate: agg[n] = sum_{e in CSR[n]} h[src[e]] ----
// one wave (64 lanes) per node; VEC = F/64 floats per lane.
template<int F>
__global__ __launch_bounds__(256) void gather_agg_k(
    const float* __restrict__ h, const int* __restrict__ row_ptr,
    const int* __restrict__ csr_src, float* __restrict__ agg) {
  constexpr int VEC = F / 64;
  int wave = (blockIdx.x * 256 + threadIdx.x) >> 6;
  int lane = threadIdx.x & 63;
  if (wave >= N_NODES) return;
  int beg = row_ptr[wave], end = row_ptr[wave + 1];
  float acc[VEC];
#pragma unroll
  for (int v = 0; v < VEC; ++v) acc[v] = 0.f;
  int e = beg;
  for (; e + 1 < end; e += 2) {     // 2x unroll: two independent loads in flight
    int s0 = csr_src[e], s1 = csr_src[e + 1];
    const float* p0 = h + (size_t)s0 * F + lane * VEC;
    const float* p1 = h + (size_t)s1 * F + lane * VEC;
    if (VEC == 2) {
      float2 a = *reinterpret_cast<const float2*>(p0);
      float2 b = *reinterpret_cast<const float2*>(p1);
      acc[0] += a.x + b.x; acc[1] += a.y + b.y;
    } else {
      acc[0] += p0[0] + p1[0];
    }
  }
  if (e < end) {
    int s0 = csr_src[e];
    const float* p0 = h + (size_t)s0 * F + lane * VEC;
#pragma unroll
    for (int v = 0; v < VEC; ++v) acc[v] += p0[v];
  }
  float* a = agg + (size_t)wave * F + lane * VEC;
  if (VEC == 2) *reinterpret_cast<float2*>(a) = make_float2(acc[0], acc[1]);
  else a[0] = acc[0];
}

// ------------- fused GEMM+bias+ReLU: out = relu((x+agg) @ W + b) -------------
template<int K>
__global__ __launch_bounds__(256) void gemm_relu_k(
    const float* __restrict__ x, const float* __restrict__ agg,
    const float* __restrict__ W, const float* __restrict__ bias,
    float* __restrict__ out, int M) {
  constexpr int N = 128, ROWS = 32, KB = 64;
  __shared__ float Ws[KB][N];
  __shared__ float xs[ROWS][K];
  __shared__ float bs[N];

  int tid = threadIdx.x;
  int row0 = blockIdx.x * ROWS;
  if (tid < N) bs[tid] = bias[tid];

  for (int i = tid; i < ROWS * K / 4; i += 256) {
    int r  = i / (K / 4);
    int kk = (i % (K / 4)) * 4;
    int row = row0 + r;
    float4 s = make_float4(0.f, 0.f, 0.f, 0.f);
    if (row < M) {
      float4 xv = *reinterpret_cast<const float4*>(x   + (size_t)row * K + kk);
      float4 av = *reinterpret_cast<const float4*>(agg + (size_t)row * K + kk);
      s = make_float4(xv.x + av.x, xv.y + av.y, xv.z + av.z, xv.w + av.w);
    }
    *reinterpret_cast<float4*>(&xs[r][kk]) = s;
  }

  int colg = tid & 31;
  int rowg = tid >> 5;

  float acc[4][4];
#pragma unroll
  for (int r = 0; r < 4; ++r)
#pragma unroll
    for (int c = 0; c < 4; ++c) acc[r][c] = 0.f;

  for (int kb = 0; kb < K; kb += KB) {
    __syncthreads();
    for (int i = tid; i < KB * N / 4; i += 256) {
      reinterpret_cast<float4*>(&Ws[0][0])[i] =
          reinterpret_cast<const float4*>(W + (size_t)kb * N)[i];
    }
    __syncthreads();
#pragma unroll 8
    for (int k = 0; k < KB; ++k) {
      float4 w4 = *reinterpret_cast<const float4*>(&Ws[k][colg * 4]);
      float x0 = xs[rowg * 4 + 0][kb + k];
      float x1 = xs[rowg * 4 + 1][kb + k];
      float x2 = xs[rowg * 4 + 2][kb + k];
      float x3 = xs[rowg * 4 + 3][kb + k];
      acc[0][0] = fmaf(x0, w4.x, acc[0][0]); acc[0][1] = fmaf(x0, w4.y, acc[0][1]);
      acc[0][2] = fmaf(x0, w4.z, acc[0][2]); acc[0][3] = fmaf(x0, w4.w, acc[0][3]);
      acc[1][0] = fmaf(x1, w4.x, acc[1][0]); acc[1][1] = fmaf(x1, w4.y, acc[1][1]);
      acc[1][2] = fmaf(x1, w4.z, acc[1][2]); acc[1][3] = fmaf(x1, w4.w, acc[1][3]);
      acc[2][0] = fmaf(x2, w4.x, acc[2][0]); acc[2][1] = fmaf(x2, w4.y, acc[2][1]);
      acc[2][2] = fmaf(x2, w4.z, acc[2][2]); acc[2][3] = fmaf(x2, w4.w, acc[2][3]);
      acc[3][0] = fmaf(x3, w4.x, acc[3][0]); acc[3][1] = fmaf(x3, w4.y, acc[3][1]);
      acc[3][2] = fmaf(x3, w4.z, acc[3][2]); acc[3][3] = fmaf(x3, w4.w, acc[3][3]);
    }
  }

#pragma unroll
  for (int r = 0; r < 4; ++r) {
    int row = row0 + rowg * 4 + r;
    if (row < M) {
      float4 o;
      o.x = fmaxf(acc[r][0] + bs[colg * 4 + 0], 0.f);
      o.y = fmaxf(acc[r][1] + bs[colg * 4 + 1], 0.f);
      o.z = fmaxf(acc[r][2] + bs[colg * 4 + 2], 0.f);
      o.w = fmaxf(acc[r][3] + bs[colg * 4 + 3], 0.f);
      *reinterpret_cast<float4*>(out + (size_t)row * N + colg * 4) = o;
    }
  }
}

// ---------------- per-graph sum + count (atomics; small) ----------------
__global__ __launch_bounds__(256) void pool_sum_k(
    const float* __restrict__ h, const int* __restrict__ batch,
    float* __restrict__ pooled, float* __restrict__ counts) {
  int idx = blockIdx.x * 256 + threadIdx.x;
  int node = idx >> 5;
  int c = (idx & 31) * 4;
  if (node >= N_NODES) return;
  int g = batch[node];
  float4 v = *reinterpret_cast<const float4*>(h + (size_t)node * DIM + c);
  float* p = pooled + (size_t)g * DIM + c;
  atomicAdd(p + 0, v.x);
  atomicAdd(p + 1, v.y);
  atomicAdd(p + 2, v.z);
  atomicAdd(p + 3, v.w);
  if (c == 0) atomicAdd(counts + g, 1.0f);
}

__global__ __launch_bounds__(128) void post_mlp_k(
    const float* __restrict__ pooled, const float* __restrict__ counts,
    const float* __restrict__ W, const float* __restrict__ bias,
    float* __restrict__ out) {
  __shared__ float xs[DIM];
  int g = blockIdx.x;
  int col = threadIdx.x;
  float cnt = fmaxf(counts[g], 1.0f);
  xs[col] = pooled[(size_t)g * DIM + col] / cnt;
  __syncthreads();
  float acc = bias[col];
  for (int k = 0; k < DIM; ++k)
    acc = fmaf(xs[k], W[(size_t)k * DIM + col], acc);
  out[(size_t)g * DIM + col] = fmaxf(acc, 0.f);
}

extern "C" void kernel_launch(void* const* d_in, const int* in_sizes, int n_in,
                              void* d_out, int out_size, void* d_ws, size_t ws_size,
                              hipStream_t stream) {
  const float* x    = (const float*)d_in[0];
  const int*   ei   = (const int*)d_in[1];
  const int*   batch= (const int*)d_in[2];
  const float* w0 = (const float*)d_in[3];  const float* b0 = (const float*)d_in[4];
  const float* w1 = (const float*)d_in[5];  const float* b1 = (const float*)d_in[6];
  const float* w2 = (const float*)d_in[7];  const float* b2 = (const float*)d_in[8];
  const float* w3 = (const float*)d_in[9];  const float* b3 = (const float*)d_in[10];
  const float* wp = (const float*)d_in[11]; const float* bp = (const float*)d_in[12];
  float* out = (float*)d_out;

  const int* src = ei;
  const int* dst = ei + N_EDGES;

  // workspace layout (fp32/int32):
  // agg[50000*128] | h[50000*128] | pooled[1024*128] | counts[1024]
  // | cnt[50000] | row_ptr[50001] | fill[50000] | csr_src[600000]
  float* agg    = (float*)d_ws;
  float* h      = agg + (size_t)N_NODES * DIM;
  float* pooled = h + (size_t)N_NODES * DIM;
  float* counts = pooled + (size_t)N_GRAPHS * DIM;
  int*   cnt     = (int*)(counts + N_GRAPHS);
  int*   row_ptr = cnt + N_NODES;
  int*   fill    = row_ptr + (N_NODES + 1);
  int*   csr_src = fill + N_NODES;

  // ---- CSR build (per call; harness re-poisons ws) ----
  hipMemsetAsync(cnt, 0, (size_t)N_NODES * 2 * sizeof(int) + sizeof(int), stream); // cnt + row_ptr head (fill zeroed below)
  hipMemsetAsync(fill, 0, (size_t)N_NODES * sizeof(int), stream);
  hist_k<<<(N_EDGES + 255) / 256, 256, 0, stream>>>(dst, cnt);
  scan_k<<<1, 256, 0, stream>>>(cnt, row_ptr);
  fill_k<<<(N_EDGES + 255) / 256, 256, 0, stream>>>(src, dst, row_ptr, fill, csr_src);

  // ---- layer 0: K=64 -> 128 ----
  gather_agg_k<N_FEAT><<<(N_NODES * 64 + 255) / 256, 256, 0, stream>>>(x, row_ptr, csr_src, agg);
  gemm_relu_k<N_FEAT><<<(N_NODES + 31) / 32, 256, 0, stream>>>(x, agg, w0, b0, h, N_NODES);

  // ---- layers 1..3: K=128 -> 128 ----
  const float* Wl[3] = {w1, w2, w3};
  const float* Bl[3] = {b1, b2, b3};
  for (int l = 0; l < 3; ++l) {
    gather_agg_k<DIM><<<(N_NODES * 64 + 255) / 256, 256, 0, stream>>>(h, row_ptr, csr_src, agg);
    gemm_relu_k<DIM><<<(N_NODES + 31) / 32, 256, 0, stream>>>(h, agg, Wl[l], Bl[l], h, N_NODES);
  }

  // ---- mean pool + post MLP ----
  hipMemsetAsync(pooled, 0, ((size_t)N_GRAPHS * DIM + N_GRAPHS) * sizeof(float), stream);
  {
    int total = N_NODES * (DIM / 4);
    pool_sum_k<<<(total + 255) / 256, 256, 0, stream>>>(h, batch, pooled, counts);
  }
  post_mlp_k<<<N_GRAPHS, 128, 0, stream>>>(pooled, counts, wp, bp, out);
}

// Round 3
// 644.625 us; speedup vs baseline: 6.0560x; 1.0310x over previous
//
#include <hip/hip_runtime.h>

// GIN forward, round 3:
//  - fuse gather-aggregate + GEMM+bias+ReLU into one kernel per layer
//    (agg round-trip eliminated; h double-buffered)
//  - mean-pool via sorted-batch binary search (no atomics) fused with post-MLP

#define N_NODES  50000
#define N_EDGES  600000
#define N_FEAT   64
#define DIM      128
#define N_GRAPHS 1024

// ---------------- CSR build ----------------
__global__ __launch_bounds__(256) void hist_k(
    const int* __restrict__ dst, int* __restrict__ cnt) {
  int e = blockIdx.x * 256 + threadIdx.x;
  if (e < N_EDGES) atomicAdd(&cnt[dst[e]], 1);
}

__global__ __launch_bounds__(256) void scan_k(
    const int* __restrict__ cnt, int* __restrict__ row_ptr) {
  __shared__ int sums[256];
  const int T = 256;
  const int chunk = (N_NODES + T - 1) / T;
  int t = threadIdx.x;
  int base = t * chunk;
  int n = min(chunk, max(0, N_NODES - base));
  int local = 0;
  for (int i = 0; i < n; ++i) local += cnt[base + i];
  sums[t] = local;
  __syncthreads();
  for (int off = 1; off < T; off <<= 1) {
    int v = (t >= off) ? sums[t - off] : 0;
    __syncthreads();
    sums[t] += v;
    __syncthreads();
  }
  int run = sums[t] - local;
  for (int i = 0; i < n; ++i) {
    row_ptr[base + i] = run;
    run += cnt[base + i];
  }
  if (t == T - 1) row_ptr[N_NODES] = run;
}

__global__ __launch_bounds__(256) void fill_k(
    const int* __restrict__ src, const int* __restrict__ dst,
    const int* __restrict__ row_ptr, int* __restrict__ fill,
    int* __restrict__ csr_src) {
  int e = blockIdx.x * 256 + threadIdx.x;
  if (e >= N_EDGES) return;
  int d = dst[e];
  int pos = row_ptr[d] + atomicAdd(&fill[d], 1);
  csr_src[pos] = src[e];
}

// ------ fused layer: hout = relu((hin + gather_sum(hin)) @ W + b) ------
// Block = 32 rows. Phase 1: 4 waves gather 8 nodes each into xs (register
// accumulate, one LDS write per row). Phase 2: 32x128 register-blocked GEMM.
template<int K>
__global__ __launch_bounds__(256) void fused_gin_k(
    const float* __restrict__ hin, const int* __restrict__ row_ptr,
    const int* __restrict__ csr_src,
    const float* __restrict__ W, const float* __restrict__ bias,
    float* __restrict__ hout, int M) {
  constexpr int N = 128, ROWS = 32, KB = 64, VEC = K / 64;
  __shared__ float Ws[KB][N];
  __shared__ float xs[ROWS][K];
  __shared__ float bs[N];

  int tid  = threadIdx.x;
  int lane = tid & 63;
  int wv   = tid >> 6;
  int row0 = blockIdx.x * ROWS;
  if (tid < N) bs[tid] = bias[tid];

  // ---- phase 1: xs[r] = hin[node] + sum_e hin[csr_src[e]] ----
  for (int r = wv; r < ROWS; r += 4) {
    int node = row0 + r;
    float acc[VEC];
#pragma unroll
    for (int v = 0; v < VEC; ++v) acc[v] = 0.f;
    if (node < M) {
      const float* ps = hin + (size_t)node * K + lane * VEC;
#pragma unroll
      for (int v = 0; v < VEC; ++v) acc[v] = ps[v];
      int beg = row_ptr[node], end = row_ptr[node + 1];
      int e = beg;
      for (; e + 3 < end; e += 4) {     // 4x unroll for ILP
        int s0 = csr_src[e], s1 = csr_src[e+1], s2 = csr_src[e+2], s3 = csr_src[e+3];
        const float* p0 = hin + (size_t)s0 * K + lane * VEC;
        const float* p1 = hin + (size_t)s1 * K + lane * VEC;
        const float* p2 = hin + (size_t)s2 * K + lane * VEC;
        const float* p3 = hin + (size_t)s3 * K + lane * VEC;
        if (VEC == 2) {
          float2 a = *reinterpret_cast<const float2*>(p0);
          float2 b = *reinterpret_cast<const float2*>(p1);
          float2 c = *reinterpret_cast<const float2*>(p2);
          float2 d = *reinterpret_cast<const float2*>(p3);
          acc[0] += (a.x + b.x) + (c.x + d.x);
          acc[1] += (a.y + b.y) + (c.y + d.y);
        } else {
          acc[0] += (p0[0] + p1[0]) + (p2[0] + p3[0]);
        }
      }
      for (; e < end; ++e) {
        const float* p0 = hin + (size_t)csr_src[e] * K + lane * VEC;
#pragma unroll
        for (int v = 0; v < VEC; ++v) acc[v] += p0[v];
      }
    }
    if (VEC == 2)
      *reinterpret_cast<float2*>(&xs[r][lane * 2]) = make_float2(acc[0], acc[1]);
    else
      xs[r][lane] = acc[0];
  }

  // ---- phase 2: GEMM ----
  int colg = tid & 31;
  int rowg = tid >> 5;
  float acc[4][4];
#pragma unroll
  for (int r = 0; r < 4; ++r)
#pragma unroll
    for (int c = 0; c < 4; ++c) acc[r][c] = 0.f;

  for (int kb = 0; kb < K; kb += KB) {
    __syncthreads();   // xs ready (first iter); Ws consumed (later iters)
    for (int i = tid; i < KB * N / 4; i += 256) {
      reinterpret_cast<float4*>(&Ws[0][0])[i] =
          reinterpret_cast<const float4*>(W + (size_t)kb * N)[i];
    }
    __syncthreads();
#pragma unroll 8
    for (int k = 0; k < KB; ++k) {
      float4 w4 = *reinterpret_cast<const float4*>(&Ws[k][colg * 4]);
      float x0 = xs[rowg * 4 + 0][kb + k];
      float x1 = xs[rowg * 4 + 1][kb + k];
      float x2 = xs[rowg * 4 + 2][kb + k];
      float x3 = xs[rowg * 4 + 3][kb + k];
      acc[0][0] = fmaf(x0, w4.x, acc[0][0]); acc[0][1] = fmaf(x0, w4.y, acc[0][1]);
      acc[0][2] = fmaf(x0, w4.z, acc[0][2]); acc[0][3] = fmaf(x0, w4.w, acc[0][3]);
      acc[1][0] = fmaf(x1, w4.x, acc[1][0]); acc[1][1] = fmaf(x1, w4.y, acc[1][1]);
      acc[1][2] = fmaf(x1, w4.z, acc[1][2]); acc[1][3] = fmaf(x1, w4.w, acc[1][3]);
      acc[2][0] = fmaf(x2, w4.x, acc[2][0]); acc[2][1] = fmaf(x2, w4.y, acc[2][1]);
      acc[2][2] = fmaf(x2, w4.z, acc[2][2]); acc[2][3] = fmaf(x2, w4.w, acc[2][3]);
      acc[3][0] = fmaf(x3, w4.x, acc[3][0]); acc[3][1] = fmaf(x3, w4.y, acc[3][1]);
      acc[3][2] = fmaf(x3, w4.z, acc[3][2]); acc[3][3] = fmaf(x3, w4.w, acc[3][3]);
    }
  }

#pragma unroll
  for (int r = 0; r < 4; ++r) {
    int row = row0 + rowg * 4 + r;
    if (row < M) {
      float4 o;
      o.x = fmaxf(acc[r][0] + bs[colg * 4 + 0], 0.f);
      o.y = fmaxf(acc[r][1] + bs[colg * 4 + 1], 0.f);
      o.z = fmaxf(acc[r][2] + bs[colg * 4 + 2], 0.f);
      o.w = fmaxf(acc[r][3] + bs[colg * 4 + 3], 0.f);
      *reinterpret_cast<float4*>(hout + (size_t)row * N + colg * 4) = o;
    }
  }
}

// ---- fused mean-pool (sorted batch, binary search) + post-MLP ----
__global__ __launch_bounds__(128) void pool_post_k(
    const float* __restrict__ h, const int* __restrict__ batch,
    const float* __restrict__ W, const float* __restrict__ bias,
    float* __restrict__ out) {
  __shared__ float xs[DIM];
  int g = blockIdx.x;
  int col = threadIdx.x;
  // lower_bound(batch, g) and lower_bound(batch, g+1) — wave-uniform
  int lo = 0, hi = N_NODES;
  while (lo < hi) { int mid = (lo + hi) >> 1; if (batch[mid] < g) lo = mid + 1; else hi = mid; }
  int beg = lo;
  hi = N_NODES;
  while (lo < hi) { int mid = (lo + hi) >> 1; if (batch[mid] < g + 1) lo = mid + 1; else hi = mid; }
  int end = lo;

  float acc = 0.f;
  for (int n = beg; n < end; ++n) acc += h[(size_t)n * DIM + col];
  float cnt = fmaxf((float)(end - beg), 1.0f);
  xs[col] = acc / cnt;
  __syncthreads();
  float o = bias[col];
  for (int k = 0; k < DIM; ++k)
    o = fmaf(xs[k], W[(size_t)k * DIM + col], o);
  out[(size_t)g * DIM + col] = fmaxf(o, 0.f);
}

extern "C" void kernel_launch(void* const* d_in, const int* in_sizes, int n_in,
                              void* d_out, int out_size, void* d_ws, size_t ws_size,
                              hipStream_t stream) {
  const float* x    = (const float*)d_in[0];
  const int*   ei   = (const int*)d_in[1];
  const int*   batch= (const int*)d_in[2];
  const float* w0 = (const float*)d_in[3];  const float* b0 = (const float*)d_in[4];
  const float* w1 = (const float*)d_in[5];  const float* b1 = (const float*)d_in[6];
  const float* w2 = (const float*)d_in[7];  const float* b2 = (const float*)d_in[8];
  const float* w3 = (const float*)d_in[9];  const float* b3 = (const float*)d_in[10];
  const float* wp = (const float*)d_in[11]; const float* bp = (const float*)d_in[12];
  float* out = (float*)d_out;

  const int* src = ei;
  const int* dst = ei + N_EDGES;

  // workspace: h1[50000*128] | h2[50000*128] | cnt[50000] | fill[50000]
  //          | row_ptr[50001] | csr_src[600000]
  float* h1 = (float*)d_ws;
  float* h2 = h1 + (size_t)N_NODES * DIM;
  int*   cnt     = (int*)(h2 + (size_t)N_NODES * DIM);
  int*   fill    = cnt + N_NODES;
  int*   row_ptr = fill + N_NODES;
  int*   csr_src = row_ptr + (N_NODES + 1);

  // ---- CSR build ----
  hipMemsetAsync(cnt, 0, (size_t)2 * N_NODES * sizeof(int), stream);  // cnt + fill
  hist_k<<<(N_EDGES + 255) / 256, 256, 0, stream>>>(dst, cnt);
  scan_k<<<1, 256, 0, stream>>>(cnt, row_ptr);
  fill_k<<<(N_EDGES + 255) / 256, 256, 0, stream>>>(src, dst, row_ptr, fill, csr_src);

  // ---- 4 fused layers (h double-buffered) ----
  int grid = (N_NODES + 31) / 32;
  fused_gin_k<N_FEAT><<<grid, 256, 0, stream>>>(x,  row_ptr, csr_src, w0, b0, h1, N_NODES);
  fused_gin_k<DIM>   <<<grid, 256, 0, stream>>>(h1, row_ptr, csr_src, w1, b1, h2, N_NODES);
  fused_gin_k<DIM>   <<<grid, 256, 0, stream>>>(h2, row_ptr, csr_src, w2, b2, h1, N_NODES);
  fused_gin_k<DIM>   <<<grid, 256, 0, stream>>>(h1, row_ptr, csr_src, w3, b3, h2, N_NODES);

  // ---- pool + post-MLP ----
  pool_post_k<<<N_GRAPHS, 128, 0, stream>>>(h2, batch, wp, bp, out);
}

// Round 4
// 538.685 us; speedup vs baseline: 7.2470x; 1.1967x over previous
//
#include <hip/hip_runtime.h>

// GIN forward, round 4: linearity split. Per layer:
//   y = h @ W          (dense LDS-tiled fp32 GEMM, no gather coupling)
//   h' = relu(y[i] + sum_{j in N(i)} y[j] + b)   (standalone gather, 0 LDS,
//                                                 8-deep ILP, max occupancy)
// CSR scan upgraded to 1024 threads. Pool+postMLP unchanged (sorted batch).

#define N_NODES  50000
#define N_EDGES  600000
#define N_FEAT   64
#define DIM      128
#define N_GRAPHS 1024

// ---------------- CSR build ----------------
__global__ __launch_bounds__(256) void hist_k(
    const int* __restrict__ dst, int* __restrict__ cnt) {
  int e = blockIdx.x * 256 + threadIdx.x;
  if (e < N_EDGES) atomicAdd(&cnt[dst[e]], 1);
}

__global__ __launch_bounds__(1024) void scan_k(
    const int* __restrict__ cnt, int* __restrict__ row_ptr) {
  __shared__ int sums[1024];
  const int T = 1024;
  const int chunk = (N_NODES + T - 1) / T;   // 49
  int t = threadIdx.x;
  int base = t * chunk;
  int n = min(chunk, max(0, N_NODES - base));
  int local = 0;
  for (int i = 0; i < n; ++i) local += cnt[base + i];
  sums[t] = local;
  __syncthreads();
  for (int off = 1; off < T; off <<= 1) {
    int v = (t >= off) ? sums[t - off] : 0;
    __syncthreads();
    sums[t] += v;
    __syncthreads();
  }
  int run = sums[t] - local;   // exclusive prefix
  for (int i = 0; i < n; ++i) {
    row_ptr[base + i] = run;
    run += cnt[base + i];
  }
  if (t == T - 1) row_ptr[N_NODES] = run;
}

__global__ __launch_bounds__(256) void fill_k(
    const int* __restrict__ src, const int* __restrict__ dst,
    const int* __restrict__ row_ptr, int* __restrict__ fill,
    int* __restrict__ csr_src) {
  int e = blockIdx.x * 256 + threadIdx.x;
  if (e >= N_EDGES) return;
  int d = dst[e];
  int pos = row_ptr[d] + atomicAdd(&fill[d], 1);
  csr_src[pos] = src[e];
}

// ---------------- dense GEMM: y = x @ W  (M x K) @ (K x 128) ----------------
template<int K>
__global__ __launch_bounds__(256) void gemm_k(
    const float* __restrict__ x, const float* __restrict__ W,
    float* __restrict__ y, int M) {
  constexpr int N = 128, ROWS = 32, KB = 64;
  __shared__ float Ws[KB][N];
  __shared__ float xs[ROWS][K];

  int tid = threadIdx.x;
  int row0 = blockIdx.x * ROWS;

  for (int i = tid; i < ROWS * K / 4; i += 256) {
    int r  = i / (K / 4);
    int kk = (i % (K / 4)) * 4;
    int row = row0 + r;
    float4 s = make_float4(0.f, 0.f, 0.f, 0.f);
    if (row < M) s = *reinterpret_cast<const float4*>(x + (size_t)row * K + kk);
    *reinterpret_cast<float4*>(&xs[r][kk]) = s;
  }

  int colg = tid & 31;
  int rowg = tid >> 5;
  float acc[4][4];
#pragma unroll
  for (int r = 0; r < 4; ++r)
#pragma unroll
    for (int c = 0; c < 4; ++c) acc[r][c] = 0.f;

  for (int kb = 0; kb < K; kb += KB) {
    __syncthreads();
    for (int i = tid; i < KB * N / 4; i += 256) {
      reinterpret_cast<float4*>(&Ws[0][0])[i] =
          reinterpret_cast<const float4*>(W + (size_t)kb * N)[i];
    }
    __syncthreads();
#pragma unroll 8
    for (int k = 0; k < KB; ++k) {
      float4 w4 = *reinterpret_cast<const float4*>(&Ws[k][colg * 4]);
      float x0 = xs[rowg * 4 + 0][kb + k];
      float x1 = xs[rowg * 4 + 1][kb + k];
      float x2 = xs[rowg * 4 + 2][kb + k];
      float x3 = xs[rowg * 4 + 3][kb + k];
      acc[0][0] = fmaf(x0, w4.x, acc[0][0]); acc[0][1] = fmaf(x0, w4.y, acc[0][1]);
      acc[0][2] = fmaf(x0, w4.z, acc[0][2]); acc[0][3] = fmaf(x0, w4.w, acc[0][3]);
      acc[1][0] = fmaf(x1, w4.x, acc[1][0]); acc[1][1] = fmaf(x1, w4.y, acc[1][1]);
      acc[1][2] = fmaf(x1, w4.z, acc[1][2]); acc[1][3] = fmaf(x1, w4.w, acc[1][3]);
      acc[2][0] = fmaf(x2, w4.x, acc[2][0]); acc[2][1] = fmaf(x2, w4.y, acc[2][1]);
      acc[2][2] = fmaf(x2, w4.z, acc[2][2]); acc[2][3] = fmaf(x2, w4.w, acc[2][3]);
      acc[3][0] = fmaf(x3, w4.x, acc[3][0]); acc[3][1] = fmaf(x3, w4.y, acc[3][1]);
      acc[3][2] = fmaf(x3, w4.z, acc[3][2]); acc[3][3] = fmaf(x3, w4.w, acc[3][3]);
    }
  }

#pragma unroll
  for (int r = 0; r < 4; ++r) {
    int row = row0 + rowg * 4 + r;
    if (row < M) {
      float4 o = make_float4(acc[r][0], acc[r][1], acc[r][2], acc[r][3]);
      *reinterpret_cast<float4*>(y + (size_t)row * N + colg * 4) = o;
    }
  }
}

// ---- gather + bias + relu: h[i] = relu(y[i] + sum_e y[csr_src[e]] + b) ----
// one wave per node, float2 per lane, 8-deep independent loads, zero LDS.
__global__ __launch_bounds__(256) void gather_relu_k(
    const float* __restrict__ y, const int* __restrict__ row_ptr,
    const int* __restrict__ csr_src, const float* __restrict__ bias,
    float* __restrict__ hout) {
  int wave = (blockIdx.x * 256 + threadIdx.x) >> 6;
  int lane = threadIdx.x & 63;
  if (wave >= N_NODES) return;
  int beg = row_ptr[wave], end = row_ptr[wave + 1];

  float2 self = *reinterpret_cast<const float2*>(y + (size_t)wave * DIM + lane * 2);
  float acc0 = self.x, acc1 = self.y;

  int e = beg;
  for (; e + 7 < end; e += 8) {
    int s0 = csr_src[e+0], s1 = csr_src[e+1], s2 = csr_src[e+2], s3 = csr_src[e+3];
    int s4 = csr_src[e+4], s5 = csr_src[e+5], s6 = csr_src[e+6], s7 = csr_src[e+7];
    float2 v0 = *reinterpret_cast<const float2*>(y + (size_t)s0 * DIM + lane * 2);
    float2 v1 = *reinterpret_cast<const float2*>(y + (size_t)s1 * DIM + lane * 2);
    float2 v2 = *reinterpret_cast<const float2*>(y + (size_t)s2 * DIM + lane * 2);
    float2 v3 = *reinterpret_cast<const float2*>(y + (size_t)s3 * DIM + lane * 2);
    float2 v4 = *reinterpret_cast<const float2*>(y + (size_t)s4 * DIM + lane * 2);
    float2 v5 = *reinterpret_cast<const float2*>(y + (size_t)s5 * DIM + lane * 2);
    float2 v6 = *reinterpret_cast<const float2*>(y + (size_t)s6 * DIM + lane * 2);
    float2 v7 = *reinterpret_cast<const float2*>(y + (size_t)s7 * DIM + lane * 2);
    acc0 += ((v0.x + v1.x) + (v2.x + v3.x)) + ((v4.x + v5.x) + (v6.x + v7.x));
    acc1 += ((v0.y + v1.y) + (v2.y + v3.y)) + ((v4.y + v5.y) + (v6.y + v7.y));
  }
  for (; e + 1 < end; e += 2) {
    int s0 = csr_src[e], s1 = csr_src[e+1];
    float2 v0 = *reinterpret_cast<const float2*>(y + (size_t)s0 * DIM + lane * 2);
    float2 v1 = *reinterpret_cast<const float2*>(y + (size_t)s1 * DIM + lane * 2);
    acc0 += v0.x + v1.x;
    acc1 += v0.y + v1.y;
  }
  if (e < end) {
    float2 v0 = *reinterpret_cast<const float2*>(y + (size_t)csr_src[e] * DIM + lane * 2);
    acc0 += v0.x; acc1 += v0.y;
  }

  float2 b2 = *reinterpret_cast<const float2*>(bias + lane * 2);
  float2 o = make_float2(fmaxf(acc0 + b2.x, 0.f), fmaxf(acc1 + b2.y, 0.f));
  *reinterpret_cast<float2*>(hout + (size_t)wave * DIM + lane * 2) = o;
}

// ---- fused mean-pool (sorted batch, binary search) + post-MLP ----
__global__ __launch_bounds__(128) void pool_post_k(
    const float* __restrict__ h, const int* __restrict__ batch,
    const float* __restrict__ W, const float* __restrict__ bias,
    float* __restrict__ out) {
  __shared__ float xs[DIM];
  int g = blockIdx.x;
  int col = threadIdx.x;
  int lo = 0, hi = N_NODES;
  while (lo < hi) { int mid = (lo + hi) >> 1; if (batch[mid] < g) lo = mid + 1; else hi = mid; }
  int beg = lo;
  hi = N_NODES;
  while (lo < hi) { int mid = (lo + hi) >> 1; if (batch[mid] < g + 1) lo = mid + 1; else hi = mid; }
  int end = lo;

  float acc = 0.f;
  for (int n = beg; n < end; ++n) acc += h[(size_t)n * DIM + col];
  float cnt = fmaxf((float)(end - beg), 1.0f);
  xs[col] = acc / cnt;
  __syncthreads();
  float o = bias[col];
  for (int k = 0; k < DIM; ++k)
    o = fmaf(xs[k], W[(size_t)k * DIM + col], o);
  out[(size_t)g * DIM + col] = fmaxf(o, 0.f);
}

extern "C" void kernel_launch(void* const* d_in, const int* in_sizes, int n_in,
                              void* d_out, int out_size, void* d_ws, size_t ws_size,
                              hipStream_t stream) {
  const float* x    = (const float*)d_in[0];
  const int*   ei   = (const int*)d_in[1];
  const int*   batch= (const int*)d_in[2];
  const float* w0 = (const float*)d_in[3];  const float* b0 = (const float*)d_in[4];
  const float* w1 = (const float*)d_in[5];  const float* b1 = (const float*)d_in[6];
  const float* w2 = (const float*)d_in[7];  const float* b2 = (const float*)d_in[8];
  const float* w3 = (const float*)d_in[9];  const float* b3 = (const float*)d_in[10];
  const float* wp = (const float*)d_in[11]; const float* bp = (const float*)d_in[12];
  float* out = (float*)d_out;

  const int* src = ei;
  const int* dst = ei + N_EDGES;

  // workspace: A[50000*128] | B[50000*128] | cnt[50000] | fill[50000]
  //          | row_ptr[50001] | csr_src[600000]
  float* A = (float*)d_ws;                       // y (pre-activation)
  float* B = A + (size_t)N_NODES * DIM;          // h (post-gather activations)
  int*   cnt     = (int*)(B + (size_t)N_NODES * DIM);
  int*   fill    = cnt + N_NODES;
  int*   row_ptr = fill + N_NODES;
  int*   csr_src = row_ptr + (N_NODES + 1);

  // ---- CSR build ----
  hipMemsetAsync(cnt, 0, (size_t)2 * N_NODES * sizeof(int), stream);  // cnt + fill
  hist_k<<<(N_EDGES + 255) / 256, 256, 0, stream>>>(dst, cnt);
  scan_k<<<1, 1024, 0, stream>>>(cnt, row_ptr);
  fill_k<<<(N_EDGES + 255) / 256, 256, 0, stream>>>(src, dst, row_ptr, fill, csr_src);

  // ---- 4 layers: y = h@W (A), h' = relu(y + gather(y) + b) (B) ----
  int ggrid = (N_NODES * 64 + 255) / 256;   // one wave per node
  int mgrid = (N_NODES + 31) / 32;

  gemm_k<N_FEAT><<<mgrid, 256, 0, stream>>>(x, w0, A, N_NODES);
  gather_relu_k<<<ggrid, 256, 0, stream>>>(A, row_ptr, csr_src, b0, B);

  const float* Wl[3] = {w1, w2, w3};
  const float* Bl[3] = {b1, b2, b3};
  for (int l = 0; l < 3; ++l) {
    gemm_k<DIM><<<mgrid, 256, 0, stream>>>(B, Wl[l], A, N_NODES);
    gather_relu_k<<<ggrid, 256, 0, stream>>>(A, row_ptr, csr_src, Bl[l], B);
  }

  // ---- pool + post-MLP ----
  pool_post_k<<<N_GRAPHS, 128, 0, stream>>>(B, batch, wp, bp, out);
}

// Round 5
// 401.754 us; speedup vs baseline: 9.7170x; 1.3408x over previous
//
#include <hip/hip_runtime.h>
#include <hip/hip_fp16.h>

// GIN forward, round 5:
//  - 3-phase coalesced scan (replaces 76us single-block scan)
//  - y (pre-aggregation) stored fp16: halves gather L2-miss traffic
// Structure: per layer  y=h@W (fp32 math, fp16 store); h'=relu(y_i+sum_N y_j+b)

#define N_NODES  50000
#define N_EDGES  600000
#define N_FEAT   64
#define DIM      128
#define N_GRAPHS 1024
#define NB_SCAN  49   // ceil(50000/1024)

// ---------------- CSR build ----------------
__global__ __launch_bounds__(256) void hist_k(
    const int* __restrict__ dst, int* __restrict__ cnt) {
  int e = blockIdx.x * 256 + threadIdx.x;
  if (e < N_EDGES) atomicAdd(&cnt[dst[e]], 1);
}

// phase 1: per-block (1024 elems) partial sums
__global__ __launch_bounds__(256) void scan_part_k(
    const int* __restrict__ cnt, int* __restrict__ part) {
  __shared__ int ws[4];
  int t = threadIdx.x, b = blockIdx.x;
  int base = b * 1024 + t * 4;
  int s = 0;
  if (base + 3 < N_NODES) {
    int4 v = *reinterpret_cast<const int4*>(cnt + base);
    s = v.x + v.y + v.z + v.w;
  } else {
    for (int i = 0; i < 4; ++i) if (base + i < N_NODES) s += cnt[base + i];
  }
  for (int off = 32; off; off >>= 1) s += __shfl_down(s, off, 64);
  int lane = t & 63, wv = t >> 6;
  if (lane == 0) ws[wv] = s;
  __syncthreads();
  if (t == 0) part[b] = ws[0] + ws[1] + ws[2] + ws[3];
}

// phase 2: exclusive scan of NB_SCAN partials (single wave)
__global__ __launch_bounds__(64) void scan_small_k(int* __restrict__ part) {
  int t = threadIdx.x;
  int v = (t < NB_SCAN) ? part[t] : 0;
  int incl = v;
  for (int off = 1; off < 64; off <<= 1) {
    int u = __shfl_up(incl, off, 64);
    if (t >= off) incl += u;
  }
  if (t < NB_SCAN) part[t] = incl - v;
}

// phase 3: intra-block exclusive scan + block offset -> row_ptr
__global__ __launch_bounds__(256) void scan_write_k(
    const int* __restrict__ cnt, const int* __restrict__ part,
    int* __restrict__ row_ptr) {
  __shared__ int wsum[4];
  int t = threadIdx.x, b = blockIdx.x;
  int lane = t & 63, wv = t >> 6;
  int base = b * 1024 + t * 4;
  int v[4];
#pragma unroll
  for (int i = 0; i < 4; ++i) v[i] = (base + i < N_NODES) ? cnt[base + i] : 0;
  int ls = v[0] + v[1] + v[2] + v[3];
  int incl = ls;
  for (int off = 1; off < 64; off <<= 1) {
    int u = __shfl_up(incl, off, 64);
    if (lane >= off) incl += u;
  }
  if (lane == 63) wsum[wv] = incl;
  __syncthreads();
  int woff = 0;
  for (int w = 0; w < wv; ++w) woff += wsum[w];
  int off0 = part[b] + woff + (incl - ls);
  int rp0 = off0, rp1 = off0 + v[0], rp2 = rp1 + v[1], rp3 = rp2 + v[2];
  if (base + 3 < N_NODES)
    *reinterpret_cast<int4*>(row_ptr + base) = make_int4(rp0, rp1, rp2, rp3);
  else {
    int rp[4] = {rp0, rp1, rp2, rp3};
    for (int i = 0; i < 4; ++i) if (base + i < N_NODES) row_ptr[base + i] = rp[i];
  }
  if (b == 0 && t == 0) row_ptr[N_NODES] = N_EDGES;  // total count is fixed
}

__global__ __launch_bounds__(256) void fill_k(
    const int* __restrict__ src, const int* __restrict__ dst,
    const int* __restrict__ row_ptr, int* __restrict__ fill,
    int* __restrict__ csr_src) {
  int e = blockIdx.x * 256 + threadIdx.x;
  if (e >= N_EDGES) return;
  int d = dst[e];
  int pos = row_ptr[d] + atomicAdd(&fill[d], 1);
  csr_src[pos] = src[e];
}

// ------------- GEMM: y = x @ W, fp32 math, fp16 store -------------
template<int K>
__global__ __launch_bounds__(256) void gemm_k(
    const float* __restrict__ x, const float* __restrict__ W,
    __half* __restrict__ y, int M) {
  constexpr int N = 128, ROWS = 32, KB = 64;
  __shared__ float Ws[KB][N];
  __shared__ float xs[ROWS][K];

  int tid = threadIdx.x;
  int row0 = blockIdx.x * ROWS;

  for (int i = tid; i < ROWS * K / 4; i += 256) {
    int r  = i / (K / 4);
    int kk = (i % (K / 4)) * 4;
    int row = row0 + r;
    float4 s = make_float4(0.f, 0.f, 0.f, 0.f);
    if (row < M) s = *reinterpret_cast<const float4*>(x + (size_t)row * K + kk);
    *reinterpret_cast<float4*>(&xs[r][kk]) = s;
  }

  int colg = tid & 31;
  int rowg = tid >> 5;
  float acc[4][4];
#pragma unroll
  for (int r = 0; r < 4; ++r)
#pragma unroll
    for (int c = 0; c < 4; ++c) acc[r][c] = 0.f;

  for (int kb = 0; kb < K; kb += KB) {
    __syncthreads();
    for (int i = tid; i < KB * N / 4; i += 256) {
      reinterpret_cast<float4*>(&Ws[0][0])[i] =
          reinterpret_cast<const float4*>(W + (size_t)kb * N)[i];
    }
    __syncthreads();
#pragma unroll 8
    for (int k = 0; k < KB; ++k) {
      float4 w4 = *reinterpret_cast<const float4*>(&Ws[k][colg * 4]);
      float x0 = xs[rowg * 4 + 0][kb + k];
      float x1 = xs[rowg * 4 + 1][kb + k];
      float x2 = xs[rowg * 4 + 2][kb + k];
      float x3 = xs[rowg * 4 + 3][kb + k];
      acc[0][0] = fmaf(x0, w4.x, acc[0][0]); acc[0][1] = fmaf(x0, w4.y, acc[0][1]);
      acc[0][2] = fmaf(x0, w4.z, acc[0][2]); acc[0][3] = fmaf(x0, w4.w, acc[0][3]);
      acc[1][0] = fmaf(x1, w4.x, acc[1][0]); acc[1][1] = fmaf(x1, w4.y, acc[1][1]);
      acc[1][2] = fmaf(x1, w4.z, acc[1][2]); acc[1][3] = fmaf(x1, w4.w, acc[1][3]);
      acc[2][0] = fmaf(x2, w4.x, acc[2][0]); acc[2][1] = fmaf(x2, w4.y, acc[2][1]);
      acc[2][2] = fmaf(x2, w4.z, acc[2][2]); acc[2][3] = fmaf(x2, w4.w, acc[2][3]);
      acc[3][0] = fmaf(x3, w4.x, acc[3][0]); acc[3][1] = fmaf(x3, w4.y, acc[3][1]);
      acc[3][2] = fmaf(x3, w4.z, acc[3][2]); acc[3][3] = fmaf(x3, w4.w, acc[3][3]);
    }
  }

#pragma unroll
  for (int r = 0; r < 4; ++r) {
    int row = row0 + rowg * 4 + r;
    if (row < M) {
      union { __half2 h2[2]; uint2 u; } pk;
      pk.h2[0] = __floats2half2_rn(acc[r][0], acc[r][1]);
      pk.h2[1] = __floats2half2_rn(acc[r][2], acc[r][3]);
      *reinterpret_cast<uint2*>(y + (size_t)row * N + colg * 4) = pk.u;
    }
  }
}

// ---- gather + bias + relu: h[i] = relu(y[i] + sum_e y[csr_src[e]] + b) ----
// one wave per node, half2 per lane, 8-deep ILP, zero LDS, fp32 accumulate.
__global__ __launch_bounds__(256) void gather_relu_k(
    const __half* __restrict__ y, const int* __restrict__ row_ptr,
    const int* __restrict__ csr_src, const float* __restrict__ bias,
    float* __restrict__ hout) {
  const __half2* y2 = reinterpret_cast<const __half2*>(y);
  int wave = (blockIdx.x * 256 + threadIdx.x) >> 6;
  int lane = threadIdx.x & 63;
  if (wave >= N_NODES) return;
  int beg = row_ptr[wave], end = row_ptr[wave + 1];

  float2 self = __half22float2(y2[(size_t)wave * 64 + lane]);
  float acc0 = self.x, acc1 = self.y;

  int e = beg;
  for (; e + 7 < end; e += 8) {
    int s0 = csr_src[e+0], s1 = csr_src[e+1], s2 = csr_src[e+2], s3 = csr_src[e+3];
    int s4 = csr_src[e+4], s5 = csr_src[e+5], s6 = csr_src[e+6], s7 = csr_src[e+7];
    __half2 v0 = y2[(size_t)s0 * 64 + lane];
    __half2 v1 = y2[(size_t)s1 * 64 + lane];
    __half2 v2 = y2[(size_t)s2 * 64 + lane];
    __half2 v3 = y2[(size_t)s3 * 64 + lane];
    __half2 v4 = y2[(size_t)s4 * 64 + lane];
    __half2 v5 = y2[(size_t)s5 * 64 + lane];
    __half2 v6 = y2[(size_t)s6 * 64 + lane];
    __half2 v7 = y2[(size_t)s7 * 64 + lane];
    float2 f0 = __half22float2(v0), f1 = __half22float2(v1);
    float2 f2 = __half22float2(v2), f3 = __half22float2(v3);
    float2 f4 = __half22float2(v4), f5 = __half22float2(v5);
    float2 f6 = __half22float2(v6), f7 = __half22float2(v7);
    acc0 += ((f0.x + f1.x) + (f2.x + f3.x)) + ((f4.x + f5.x) + (f6.x + f7.x));
    acc1 += ((f0.y + f1.y) + (f2.y + f3.y)) + ((f4.y + f5.y) + (f6.y + f7.y));
  }
  for (; e + 1 < end; e += 2) {
    float2 f0 = __half22float2(y2[(size_t)csr_src[e]   * 64 + lane]);
    float2 f1 = __half22float2(y2[(size_t)csr_src[e+1] * 64 + lane]);
    acc0 += f0.x + f1.x;
    acc1 += f0.y + f1.y;
  }
  if (e < end) {
    float2 f0 = __half22float2(y2[(size_t)csr_src[e] * 64 + lane]);
    acc0 += f0.x; acc1 += f0.y;
  }

  float2 b2 = *reinterpret_cast<const float2*>(bias + lane * 2);
  float2 o = make_float2(fmaxf(acc0 + b2.x, 0.f), fmaxf(acc1 + b2.y, 0.f));
  *reinterpret_cast<float2*>(hout + (size_t)wave * DIM + lane * 2) = o;
}

// ---- fused mean-pool (sorted batch, binary search) + post-MLP ----
__global__ __launch_bounds__(128) void pool_post_k(
    const float* __restrict__ h, const int* __restrict__ batch,
    const float* __restrict__ W, const float* __restrict__ bias,
    float* __restrict__ out) {
  __shared__ float xs[DIM];
  int g = blockIdx.x;
  int col = threadIdx.x;
  int lo = 0, hi = N_NODES;
  while (lo < hi) { int mid = (lo + hi) >> 1; if (batch[mid] < g) lo = mid + 1; else hi = mid; }
  int beg = lo;
  hi = N_NODES;
  while (lo < hi) { int mid = (lo + hi) >> 1; if (batch[mid] < g + 1) lo = mid + 1; else hi = mid; }
  int end = lo;

  float acc = 0.f;
  for (int n = beg; n < end; ++n) acc += h[(size_t)n * DIM + col];
  float cnt = fmaxf((float)(end - beg), 1.0f);
  xs[col] = acc / cnt;
  __syncthreads();
  float o = bias[col];
  for (int k = 0; k < DIM; ++k)
    o = fmaf(xs[k], W[(size_t)k * DIM + col], o);
  out[(size_t)g * DIM + col] = fmaxf(o, 0.f);
}

extern "C" void kernel_launch(void* const* d_in, const int* in_sizes, int n_in,
                              void* d_out, int out_size, void* d_ws, size_t ws_size,
                              hipStream_t stream) {
  const float* x    = (const float*)d_in[0];
  const int*   ei   = (const int*)d_in[1];
  const int*   batch= (const int*)d_in[2];
  const float* w0 = (const float*)d_in[3];  const float* b0 = (const float*)d_in[4];
  const float* w1 = (const float*)d_in[5];  const float* b1 = (const float*)d_in[6];
  const float* w2 = (const float*)d_in[7];  const float* b2 = (const float*)d_in[8];
  const float* w3 = (const float*)d_in[9];  const float* b3 = (const float*)d_in[10];
  const float* wp = (const float*)d_in[11]; const float* bp = (const float*)d_in[12];
  float* out = (float*)d_out;

  const int* src = ei;
  const int* dst = ei + N_EDGES;

  // workspace: yA(half)[50000*128] | B(f32)[50000*128] | cnt[50000] | fill[50000]
  //          | part[64] | row_ptr[50001] | csr_src[600000]
  __half* A = (__half*)d_ws;
  float*  B = (float*)((char*)d_ws + (size_t)N_NODES * DIM * sizeof(__half));
  int* cnt     = (int*)(B + (size_t)N_NODES * DIM);
  int* fill    = cnt + N_NODES;
  int* part    = fill + N_NODES;
  int* row_ptr = part + 64;
  int* csr_src = row_ptr + (N_NODES + 1);

  // ---- CSR build ----
  hipMemsetAsync(cnt, 0, (size_t)2 * N_NODES * sizeof(int), stream);  // cnt + fill
  hist_k<<<(N_EDGES + 255) / 256, 256, 0, stream>>>(dst, cnt);
  scan_part_k <<<NB_SCAN, 256, 0, stream>>>(cnt, part);
  scan_small_k<<<1, 64, 0, stream>>>(part);
  scan_write_k<<<NB_SCAN, 256, 0, stream>>>(cnt, part, row_ptr);
  fill_k<<<(N_EDGES + 255) / 256, 256, 0, stream>>>(src, dst, row_ptr, fill, csr_src);

  // ---- 4 layers ----
  int ggrid = (N_NODES * 64 + 255) / 256;
  int mgrid = (N_NODES + 31) / 32;

  gemm_k<N_FEAT><<<mgrid, 256, 0, stream>>>(x, w0, A, N_NODES);
  gather_relu_k<<<ggrid, 256, 0, stream>>>(A, row_ptr, csr_src, b0, B);

  const float* Wl[3] = {w1, w2, w3};
  const float* Bl[3] = {b1, b2, b3};
  for (int l = 0; l < 3; ++l) {
    gemm_k<DIM><<<mgrid, 256, 0, stream>>>(B, Wl[l], A, N_NODES);
    gather_relu_k<<<ggrid, 256, 0, stream>>>(A, row_ptr, csr_src, Bl[l], B);
  }

  // ---- pool + post-MLP ----
  pool_post_k<<<N_GRAPHS, 128, 0, stream>>>(B, batch, wp, bp, out);
}

// Round 6
// 358.814 us; speedup vs baseline: 10.8798x; 1.1197x over previous
//
#include <hip/hip_runtime.h>
#include <hip/hip_fp16.h>

// GIN forward, round 6: fp16 activations end-to-end + MFMA GEMM.
//   y = h @ W   via v_mfma_f32_16x16x32_f16 (A/B fp16 LDS, fp32 acc, fp16 store)
//   h' = relu(y_i + sum_N y_j + b)  (gather fp16->fp32 acc->fp16 store)
// Fragment layouts per learn_hip m89/m120: A[m=lane&15][k=quad*8+j],
// C/D col=lane&15, row=quad*4+reg.

#define N_NODES  50000
#define N_EDGES  600000
#define N_FEAT   64
#define DIM      128
#define N_GRAPHS 1024
#define NB_SCAN  49   // ceil(50000/1024)

typedef _Float16 f16x8 __attribute__((ext_vector_type(8)));
typedef float    f32x4 __attribute__((ext_vector_type(4)));

// ---------------- CSR build ----------------
__global__ __launch_bounds__(256) void hist_k(
    const int* __restrict__ dst, int* __restrict__ cnt) {
  int e = blockIdx.x * 256 + threadIdx.x;
  if (e < N_EDGES) atomicAdd(&cnt[dst[e]], 1);
}

__global__ __launch_bounds__(256) void scan_part_k(
    const int* __restrict__ cnt, int* __restrict__ part) {
  __shared__ int ws[4];
  int t = threadIdx.x, b = blockIdx.x;
  int base = b * 1024 + t * 4;
  int s = 0;
  if (base + 3 < N_NODES) {
    int4 v = *reinterpret_cast<const int4*>(cnt + base);
    s = v.x + v.y + v.z + v.w;
  } else {
    for (int i = 0; i < 4; ++i) if (base + i < N_NODES) s += cnt[base + i];
  }
  for (int off = 32; off; off >>= 1) s += __shfl_down(s, off, 64);
  int lane = t & 63, wv = t >> 6;
  if (lane == 0) ws[wv] = s;
  __syncthreads();
  if (t == 0) part[b] = ws[0] + ws[1] + ws[2] + ws[3];
}

__global__ __launch_bounds__(64) void scan_small_k(int* __restrict__ part) {
  int t = threadIdx.x;
  int v = (t < NB_SCAN) ? part[t] : 0;
  int incl = v;
  for (int off = 1; off < 64; off <<= 1) {
    int u = __shfl_up(incl, off, 64);
    if (t >= off) incl += u;
  }
  if (t < NB_SCAN) part[t] = incl - v;
}

__global__ __launch_bounds__(256) void scan_write_k(
    const int* __restrict__ cnt, const int* __restrict__ part,
    int* __restrict__ row_ptr) {
  __shared__ int wsum[4];
  int t = threadIdx.x, b = blockIdx.x;
  int lane = t & 63, wv = t >> 6;
  int base = b * 1024 + t * 4;
  int v[4];
#pragma unroll
  for (int i = 0; i < 4; ++i) v[i] = (base + i < N_NODES) ? cnt[base + i] : 0;
  int ls = v[0] + v[1] + v[2] + v[3];
  int incl = ls;
  for (int off = 1; off < 64; off <<= 1) {
    int u = __shfl_up(incl, off, 64);
    if (lane >= off) incl += u;
  }
  if (lane == 63) wsum[wv] = incl;
  __syncthreads();
  int woff = 0;
  for (int w = 0; w < wv; ++w) woff += wsum[w];
  int off0 = part[b] + woff + (incl - ls);
  int rp0 = off0, rp1 = off0 + v[0], rp2 = rp1 + v[1], rp3 = rp2 + v[2];
  if (base + 3 < N_NODES)
    *reinterpret_cast<int4*>(row_ptr + base) = make_int4(rp0, rp1, rp2, rp3);
  else {
    int rp[4] = {rp0, rp1, rp2, rp3};
    for (int i = 0; i < 4; ++i) if (base + i < N_NODES) row_ptr[base + i] = rp[i];
  }
  if (b == 0 && t == 0) row_ptr[N_NODES] = N_EDGES;
}

__global__ __launch_bounds__(256) void fill_k(
    const int* __restrict__ src, const int* __restrict__ dst,
    const int* __restrict__ row_ptr, int* __restrict__ fill,
    int* __restrict__ csr_src) {
  int e = blockIdx.x * 256 + threadIdx.x;
  if (e >= N_EDGES) return;
  int d = dst[e];
  int pos = row_ptr[d] + atomicAdd(&fill[d], 1);
  csr_src[pos] = src[e];
}

// ---------------- prep: x -> fp16; W[K][128] -> Wt[128][K] fp16 ----------------
__global__ __launch_bounds__(256) void xcast_k(
    const float* __restrict__ x, __half* __restrict__ xh) {
  int i = blockIdx.x * 256 + threadIdx.x;            // over N_NODES*N_FEAT/4
  if (i >= N_NODES * N_FEAT / 4) return;
  float4 v = *reinterpret_cast<const float4*>(x + (size_t)i * 4);
  union { __half2 h2[2]; uint2 u; } pk;
  pk.h2[0] = __floats2half2_rn(v.x, v.y);
  pk.h2[1] = __floats2half2_rn(v.z, v.w);
  *reinterpret_cast<uint2*>(xh + (size_t)i * 4) = pk.u;
}

__global__ __launch_bounds__(256) void wprep_k(
    const float* __restrict__ W, __half* __restrict__ Wt, int K) {
  int i = blockIdx.x * 256 + threadIdx.x;            // over K*128
  if (i >= K * 128) return;
  int k = i >> 7, n = i & 127;
  Wt[n * K + k] = __float2half(W[i]);
}

// ------------- MFMA GEMM: y[M][128] = A[M][K] @ Wt[128][K]^T, all fp16 -------------
// 256 threads = 4 waves; block computes 64 rows. Wave w: rows w*16..w*16+15,
// 8 col-tiles of 16. LDS rows padded +8 halves (16B) -> 2-way bank alias (free).
template<int K>
__global__ __launch_bounds__(256) void mfma_gemm_k(
    const __half* __restrict__ A, const __half* __restrict__ Wt,
    __half* __restrict__ y, int M) {
  constexpr int KP = K + 8;
  __shared__ __align__(16) __half As[64][KP];
  __shared__ __align__(16) __half Ws[128][KP];

  int tid = threadIdx.x;
  int row0 = blockIdx.x * 64;

  for (int i = tid; i < 64 * (K / 8); i += 256) {
    int r = i / (K / 8), c = (i % (K / 8)) * 8;
    int row = row0 + r;
    f16x8 v = {};
    if (row < M) v = *reinterpret_cast<const f16x8*>(A + (size_t)row * K + c);
    *reinterpret_cast<f16x8*>(&As[r][c]) = v;
  }
  for (int i = tid; i < 128 * (K / 8); i += 256) {
    int r = i / (K / 8), c = (i % (K / 8)) * 8;
    *reinterpret_cast<f16x8*>(&Ws[r][c]) =
        *reinterpret_cast<const f16x8*>(Wt + (size_t)r * K + c);
  }
  __syncthreads();

  int w = tid >> 6, lane = tid & 63;
  int quad = lane >> 4, m = lane & 15;

  f32x4 acc[8];
#pragma unroll
  for (int t = 0; t < 8; ++t) acc[t] = (f32x4){0.f, 0.f, 0.f, 0.f};

#pragma unroll
  for (int kk = 0; kk < K; kk += 32) {
    f16x8 a = *reinterpret_cast<const f16x8*>(&As[w * 16 + m][kk + quad * 8]);
#pragma unroll
    for (int t = 0; t < 8; ++t) {
      f16x8 b = *reinterpret_cast<const f16x8*>(&Ws[t * 16 + m][kk + quad * 8]);
      acc[t] = __builtin_amdgcn_mfma_f32_16x16x32_f16(a, b, acc[t], 0, 0, 0);
    }
  }

#pragma unroll
  for (int t = 0; t < 8; ++t) {
#pragma unroll
    for (int r = 0; r < 4; ++r) {
      int row = row0 + w * 16 + quad * 4 + r;
      if (row < M)
        y[(size_t)row * 128 + t * 16 + m] = __float2half(acc[t][r]);
    }
  }
}

// ---- gather + bias + relu: h[i] = relu(y[i] + sum_e y[csr_src[e]] + b), fp16 out ----
__global__ __launch_bounds__(256) void gather_relu_k(
    const __half* __restrict__ y, const int* __restrict__ row_ptr,
    const int* __restrict__ csr_src, const float* __restrict__ bias,
    __half* __restrict__ hout) {
  const __half2* y2 = reinterpret_cast<const __half2*>(y);
  int wave = (blockIdx.x * 256 + threadIdx.x) >> 6;
  int lane = threadIdx.x & 63;
  if (wave >= N_NODES) return;
  int beg = row_ptr[wave], end = row_ptr[wave + 1];

  float2 self = __half22float2(y2[(size_t)wave * 64 + lane]);
  float acc0 = self.x, acc1 = self.y;

  int e = beg;
  for (; e + 7 < end; e += 8) {
    int s0 = csr_src[e+0], s1 = csr_src[e+1], s2 = csr_src[e+2], s3 = csr_src[e+3];
    int s4 = csr_src[e+4], s5 = csr_src[e+5], s6 = csr_src[e+6], s7 = csr_src[e+7];
    __half2 v0 = y2[(size_t)s0 * 64 + lane];
    __half2 v1 = y2[(size_t)s1 * 64 + lane];
    __half2 v2 = y2[(size_t)s2 * 64 + lane];
    __half2 v3 = y2[(size_t)s3 * 64 + lane];
    __half2 v4 = y2[(size_t)s4 * 64 + lane];
    __half2 v5 = y2[(size_t)s5 * 64 + lane];
    __half2 v6 = y2[(size_t)s6 * 64 + lane];
    __half2 v7 = y2[(size_t)s7 * 64 + lane];
    float2 f0 = __half22float2(v0), f1 = __half22float2(v1);
    float2 f2 = __half22float2(v2), f3 = __half22float2(v3);
    float2 f4 = __half22float2(v4), f5 = __half22float2(v5);
    float2 f6 = __half22float2(v6), f7 = __half22float2(v7);
    acc0 += ((f0.x + f1.x) + (f2.x + f3.x)) + ((f4.x + f5.x) + (f6.x + f7.x));
    acc1 += ((f0.y + f1.y) + (f2.y + f3.y)) + ((f4.y + f5.y) + (f6.y + f7.y));
  }
  for (; e + 1 < end; e += 2) {
    float2 f0 = __half22float2(y2[(size_t)csr_src[e]   * 64 + lane]);
    float2 f1 = __half22float2(y2[(size_t)csr_src[e+1] * 64 + lane]);
    acc0 += f0.x + f1.x;
    acc1 += f0.y + f1.y;
  }
  if (e < end) {
    float2 f0 = __half22float2(y2[(size_t)csr_src[e] * 64 + lane]);
    acc0 += f0.x; acc1 += f0.y;
  }

  float2 b2 = *reinterpret_cast<const float2*>(bias + lane * 2);
  __half2 o = __floats2half2_rn(fmaxf(acc0 + b2.x, 0.f), fmaxf(acc1 + b2.y, 0.f));
  reinterpret_cast<__half2*>(hout)[(size_t)wave * 64 + lane] = o;
}

// ---- fused mean-pool (sorted batch) + post-MLP (fp32) ----
__global__ __launch_bounds__(128) void pool_post_k(
    const __half* __restrict__ h, const int* __restrict__ batch,
    const float* __restrict__ W, const float* __restrict__ bias,
    float* __restrict__ out) {
  __shared__ float xs[DIM];
  int g = blockIdx.x;
  int col = threadIdx.x;
  int lo = 0, hi = N_NODES;
  while (lo < hi) { int mid = (lo + hi) >> 1; if (batch[mid] < g) lo = mid + 1; else hi = mid; }
  int beg = lo;
  hi = N_NODES;
  while (lo < hi) { int mid = (lo + hi) >> 1; if (batch[mid] < g + 1) lo = mid + 1; else hi = mid; }
  int end = lo;

  float acc = 0.f;
  for (int n = beg; n < end; ++n) acc += __half2float(h[(size_t)n * DIM + col]);
  float cnt = fmaxf((float)(end - beg), 1.0f);
  xs[col] = acc / cnt;
  __syncthreads();
  float o = bias[col];
  for (int k = 0; k < DIM; ++k)
    o = fmaf(xs[k], W[(size_t)k * DIM + col], o);
  out[(size_t)g * DIM + col] = fmaxf(o, 0.f);
}

extern "C" void kernel_launch(void* const* d_in, const int* in_sizes, int n_in,
                              void* d_out, int out_size, void* d_ws, size_t ws_size,
                              hipStream_t stream) {
  const float* x    = (const float*)d_in[0];
  const int*   ei   = (const int*)d_in[1];
  const int*   batch= (const int*)d_in[2];
  const float* w0 = (const float*)d_in[3];  const float* b0 = (const float*)d_in[4];
  const float* w1 = (const float*)d_in[5];  const float* b1 = (const float*)d_in[6];
  const float* w2 = (const float*)d_in[7];  const float* b2 = (const float*)d_in[8];
  const float* w3 = (const float*)d_in[9];  const float* b3 = (const float*)d_in[10];
  const float* wp = (const float*)d_in[11]; const float* bp = (const float*)d_in[12];
  float* out = (float*)d_out;

  const int* src = ei;
  const int* dst = ei + N_EDGES;

  // ws layout: xh[50000*64]h | y[50000*128]h | h[50000*128]h
  //          | Wt0[64*128]h | Wt1..3[128*128]h | cnt | fill | part[64] | row_ptr | csr_src
  __half* xh = (__half*)d_ws;
  __half* y  = xh + (size_t)N_NODES * N_FEAT;
  __half* h  = y  + (size_t)N_NODES * DIM;
  __half* Wt0 = h + (size_t)N_NODES * DIM;
  __half* Wt1 = Wt0 + N_FEAT * DIM;
  __half* Wt2 = Wt1 + DIM * DIM;
  __half* Wt3 = Wt2 + DIM * DIM;
  int* cnt     = (int*)(Wt3 + DIM * DIM);
  int* fill    = cnt + N_NODES;
  int* part    = fill + N_NODES;
  int* row_ptr = part + 64;
  int* csr_src = row_ptr + (N_NODES + 1);

  // ---- CSR build ----
  hipMemsetAsync(cnt, 0, (size_t)2 * N_NODES * sizeof(int), stream);
  hist_k<<<(N_EDGES + 255) / 256, 256, 0, stream>>>(dst, cnt);
  scan_part_k <<<NB_SCAN, 256, 0, stream>>>(cnt, part);
  scan_small_k<<<1, 64, 0, stream>>>(part);
  scan_write_k<<<NB_SCAN, 256, 0, stream>>>(cnt, part, row_ptr);
  fill_k<<<(N_EDGES + 255) / 256, 256, 0, stream>>>(src, dst, row_ptr, fill, csr_src);

  // ---- prep: fp16 casts ----
  xcast_k<<<(N_NODES * N_FEAT / 4 + 255) / 256, 256, 0, stream>>>(x, xh);
  wprep_k<<<(N_FEAT * DIM + 255) / 256, 256, 0, stream>>>(w0, Wt0, N_FEAT);
  wprep_k<<<(DIM * DIM + 255) / 256, 256, 0, stream>>>(w1, Wt1, DIM);
  wprep_k<<<(DIM * DIM + 255) / 256, 256, 0, stream>>>(w2, Wt2, DIM);
  wprep_k<<<(DIM * DIM + 255) / 256, 256, 0, stream>>>(w3, Wt3, DIM);

  // ---- 4 layers ----
  int ggrid = (N_NODES * 64 + 255) / 256;
  int mgrid = (N_NODES + 63) / 64;

  mfma_gemm_k<N_FEAT><<<mgrid, 256, 0, stream>>>(xh, Wt0, y, N_NODES);
  gather_relu_k<<<ggrid, 256, 0, stream>>>(y, row_ptr, csr_src, b0, h);

  const __half* Wl[3] = {Wt1, Wt2, Wt3};
  const float*  Bl[3] = {b1, b2, b3};
  for (int l = 0; l < 3; ++l) {
    mfma_gemm_k<DIM><<<mgrid, 256, 0, stream>>>(h, Wl[l], y, N_NODES);
    gather_relu_k<<<ggrid, 256, 0, stream>>>(y, row_ptr, csr_src, Bl[l], h);
  }

  // ---- pool + post-MLP ----
  pool_post_k<<<N_GRAPHS, 128, 0, stream>>>(h, batch, wp, bp, out);
}

// Round 7
// 331.111 us; speedup vs baseline: 11.7901x; 1.0837x over previous
//
#include <hip/hip_runtime.h>
#include <hip/hip_fp16.h>

// GIN forward, round 7:
//  - gather: 4 nodes/wave, 16 lanes/node, f16x8 (16B) per lane -> 1KB per
//    VMEM instruction, 4 independent edge streams, 4-deep unroll
//  - single merged prep kernel (xcast + 4x W transpose/cast)
// MFMA GEMM per m89/m120 layouts: A[m=lane&15][k=quad*8+j]; C/D col=lane&15,
// row=quad*4+reg.

#define N_NODES  50000
#define N_EDGES  600000
#define N_FEAT   64
#define DIM      128
#define N_GRAPHS 1024
#define NB_SCAN  49   // ceil(50000/1024)

typedef _Float16 f16x8 __attribute__((ext_vector_type(8)));
typedef float    f32x4 __attribute__((ext_vector_type(4)));

// ---------------- CSR build ----------------
__global__ __launch_bounds__(256) void hist_k(
    const int* __restrict__ dst, int* __restrict__ cnt) {
  int e = blockIdx.x * 256 + threadIdx.x;
  if (e < N_EDGES) atomicAdd(&cnt[dst[e]], 1);
}

__global__ __launch_bounds__(256) void scan_part_k(
    const int* __restrict__ cnt, int* __restrict__ part) {
  __shared__ int ws[4];
  int t = threadIdx.x, b = blockIdx.x;
  int base = b * 1024 + t * 4;
  int s = 0;
  if (base + 3 < N_NODES) {
    int4 v = *reinterpret_cast<const int4*>(cnt + base);
    s = v.x + v.y + v.z + v.w;
  } else {
    for (int i = 0; i < 4; ++i) if (base + i < N_NODES) s += cnt[base + i];
  }
  for (int off = 32; off; off >>= 1) s += __shfl_down(s, off, 64);
  int lane = t & 63, wv = t >> 6;
  if (lane == 0) ws[wv] = s;
  __syncthreads();
  if (t == 0) part[b] = ws[0] + ws[1] + ws[2] + ws[3];
}

__global__ __launch_bounds__(64) void scan_small_k(int* __restrict__ part) {
  int t = threadIdx.x;
  int v = (t < NB_SCAN) ? part[t] : 0;
  int incl = v;
  for (int off = 1; off < 64; off <<= 1) {
    int u = __shfl_up(incl, off, 64);
    if (t >= off) incl += u;
  }
  if (t < NB_SCAN) part[t] = incl - v;
}

__global__ __launch_bounds__(256) void scan_write_k(
    const int* __restrict__ cnt, const int* __restrict__ part,
    int* __restrict__ row_ptr) {
  __shared__ int wsum[4];
  int t = threadIdx.x, b = blockIdx.x;
  int lane = t & 63, wv = t >> 6;
  int base = b * 1024 + t * 4;
  int v[4];
#pragma unroll
  for (int i = 0; i < 4; ++i) v[i] = (base + i < N_NODES) ? cnt[base + i] : 0;
  int ls = v[0] + v[1] + v[2] + v[3];
  int incl = ls;
  for (int off = 1; off < 64; off <<= 1) {
    int u = __shfl_up(incl, off, 64);
    if (lane >= off) incl += u;
  }
  if (lane == 63) wsum[wv] = incl;
  __syncthreads();
  int woff = 0;
  for (int w = 0; w < wv; ++w) woff += wsum[w];
  int off0 = part[b] + woff + (incl - ls);
  int rp0 = off0, rp1 = off0 + v[0], rp2 = rp1 + v[1], rp3 = rp2 + v[2];
  if (base + 3 < N_NODES)
    *reinterpret_cast<int4*>(row_ptr + base) = make_int4(rp0, rp1, rp2, rp3);
  else {
    int rp[4] = {rp0, rp1, rp2, rp3};
    for (int i = 0; i < 4; ++i) if (base + i < N_NODES) row_ptr[base + i] = rp[i];
  }
  if (b == 0 && t == 0) row_ptr[N_NODES] = N_EDGES;
}

__global__ __launch_bounds__(256) void fill_k(
    const int* __restrict__ src, const int* __restrict__ dst,
    const int* __restrict__ row_ptr, int* __restrict__ fill,
    int* __restrict__ csr_src) {
  int e = blockIdx.x * 256 + threadIdx.x;
  if (e >= N_EDGES) return;
  int d = dst[e];
  int pos = row_ptr[d] + atomicAdd(&fill[d], 1);
  csr_src[pos] = src[e];
}

// ---- merged prep: x->fp16 (vec4) ; W[K][128] -> Wt[128][K] fp16 ----
#define XWORK (N_NODES * N_FEAT / 4)   // 800000 float4 items
__global__ __launch_bounds__(256) void prep_k(
    const float* __restrict__ x, __half* __restrict__ xh,
    const float* __restrict__ w0, const float* __restrict__ w1,
    const float* __restrict__ w2, const float* __restrict__ w3,
    __half* __restrict__ Wt0, __half* __restrict__ Wt1,
    __half* __restrict__ Wt2, __half* __restrict__ Wt3) {
  int i = blockIdx.x * 256 + threadIdx.x;
  if (i < XWORK) {
    float4 v = *reinterpret_cast<const float4*>(x + (size_t)i * 4);
    union { __half2 h2[2]; uint2 u; } pk;
    pk.h2[0] = __floats2half2_rn(v.x, v.y);
    pk.h2[1] = __floats2half2_rn(v.z, v.w);
    *reinterpret_cast<uint2*>(xh + (size_t)i * 4) = pk.u;
    return;
  }
  int j = i - XWORK;
  if (j < N_FEAT * DIM) {               // w0: [64][128] -> Wt0[128][64]
    int k = j >> 7, n = j & 127;
    Wt0[n * N_FEAT + k] = __float2half(w0[j]);
    return;
  }
  j -= N_FEAT * DIM;
  if (j >= 3 * DIM * DIM) return;
  int wsel = j / (DIM * DIM);
  int jj = j - wsel * (DIM * DIM);
  int k = jj >> 7, n = jj & 127;
  const float* W = (wsel == 0) ? w1 : (wsel == 1) ? w2 : w3;
  __half* Wt     = (wsel == 0) ? Wt1 : (wsel == 1) ? Wt2 : Wt3;
  Wt[n * DIM + k] = __float2half(W[jj]);
}

// ------------- MFMA GEMM: y[M][128] = A[M][K] @ Wt[128][K]^T -------------
template<int K>
__global__ __launch_bounds__(256) void mfma_gemm_k(
    const __half* __restrict__ A, const __half* __restrict__ Wt,
    __half* __restrict__ y, int M) {
  constexpr int KP = K + 8;
  __shared__ __align__(16) __half As[64][KP];
  __shared__ __align__(16) __half Ws[128][KP];

  int tid = threadIdx.x;
  int row0 = blockIdx.x * 64;

  for (int i = tid; i < 64 * (K / 8); i += 256) {
    int r = i / (K / 8), c = (i % (K / 8)) * 8;
    int row = row0 + r;
    f16x8 v = {};
    if (row < M) v = *reinterpret_cast<const f16x8*>(A + (size_t)row * K + c);
    *reinterpret_cast<f16x8*>(&As[r][c]) = v;
  }
  for (int i = tid; i < 128 * (K / 8); i += 256) {
    int r = i / (K / 8), c = (i % (K / 8)) * 8;
    *reinterpret_cast<f16x8*>(&Ws[r][c]) =
        *reinterpret_cast<const f16x8*>(Wt + (size_t)r * K + c);
  }
  __syncthreads();

  int w = tid >> 6, lane = tid & 63;
  int quad = lane >> 4, m = lane & 15;

  f32x4 acc[8];
#pragma unroll
  for (int t = 0; t < 8; ++t) acc[t] = (f32x4){0.f, 0.f, 0.f, 0.f};

#pragma unroll
  for (int kk = 0; kk < K; kk += 32) {
    f16x8 a = *reinterpret_cast<const f16x8*>(&As[w * 16 + m][kk + quad * 8]);
#pragma unroll
    for (int t = 0; t < 8; ++t) {
      f16x8 b = *reinterpret_cast<const f16x8*>(&Ws[t * 16 + m][kk + quad * 8]);
      acc[t] = __builtin_amdgcn_mfma_f32_16x16x32_f16(a, b, acc[t], 0, 0, 0);
    }
  }

#pragma unroll
  for (int t = 0; t < 8; ++t) {
#pragma unroll
    for (int r = 0; r < 4; ++r) {
      int row = row0 + w * 16 + quad * 4 + r;
      if (row < M)
        y[(size_t)row * 128 + t * 16 + m] = __float2half(acc[t][r]);
    }
  }
}

// ---- gather + bias + relu: h[i] = relu(y[i] + sum_e y[csr_src[e]] + b) ----
// 16 lanes per node (f16x8 = 16B per lane), 4 nodes per wave, fp32 accum.
__global__ __launch_bounds__(256) void gather_relu_k(
    const __half* __restrict__ y, const int* __restrict__ row_ptr,
    const int* __restrict__ csr_src, const float* __restrict__ bias,
    __half* __restrict__ hout) {
  const f16x8* yv = reinterpret_cast<const f16x8*>(y);   // 16 chunks per row
  int node = (blockIdx.x * 256 + threadIdx.x) >> 4;
  int l    = threadIdx.x & 15;
  if (node >= N_NODES) return;
  int beg = row_ptr[node], end = row_ptr[node + 1];

  f16x8 self = yv[(size_t)node * 16 + l];
  float acc[8];
#pragma unroll
  for (int v = 0; v < 8; ++v) acc[v] = (float)self[v];

  int e = beg;
  for (; e + 3 < end; e += 4) {
    int s0 = csr_src[e+0], s1 = csr_src[e+1], s2 = csr_src[e+2], s3 = csr_src[e+3];
    f16x8 v0 = yv[(size_t)s0 * 16 + l];
    f16x8 v1 = yv[(size_t)s1 * 16 + l];
    f16x8 v2 = yv[(size_t)s2 * 16 + l];
    f16x8 v3 = yv[(size_t)s3 * 16 + l];
#pragma unroll
    for (int v = 0; v < 8; ++v)
      acc[v] += ((float)v0[v] + (float)v1[v]) + ((float)v2[v] + (float)v3[v]);
  }
  for (; e < end; ++e) {
    f16x8 v0 = yv[(size_t)csr_src[e] * 16 + l];
#pragma unroll
    for (int v = 0; v < 8; ++v) acc[v] += (float)v0[v];
  }

  float4 b0 = *reinterpret_cast<const float4*>(bias + l * 8);
  float4 b1 = *reinterpret_cast<const float4*>(bias + l * 8 + 4);
  f16x8 o;
  o[0] = (_Float16)fmaxf(acc[0] + b0.x, 0.f);
  o[1] = (_Float16)fmaxf(acc[1] + b0.y, 0.f);
  o[2] = (_Float16)fmaxf(acc[2] + b0.z, 0.f);
  o[3] = (_Float16)fmaxf(acc[3] + b0.w, 0.f);
  o[4] = (_Float16)fmaxf(acc[4] + b1.x, 0.f);
  o[5] = (_Float16)fmaxf(acc[5] + b1.y, 0.f);
  o[6] = (_Float16)fmaxf(acc[6] + b1.z, 0.f);
  o[7] = (_Float16)fmaxf(acc[7] + b1.w, 0.f);
  reinterpret_cast<f16x8*>(hout)[(size_t)node * 16 + l] = o;
}

// ---- fused mean-pool (sorted batch) + post-MLP (fp32) ----
__global__ __launch_bounds__(128) void pool_post_k(
    const __half* __restrict__ h, const int* __restrict__ batch,
    const float* __restrict__ W, const float* __restrict__ bias,
    float* __restrict__ out) {
  __shared__ float xs[DIM];
  int g = blockIdx.x;
  int col = threadIdx.x;
  int lo = 0, hi = N_NODES;
  while (lo < hi) { int mid = (lo + hi) >> 1; if (batch[mid] < g) lo = mid + 1; else hi = mid; }
  int beg = lo;
  hi = N_NODES;
  while (lo < hi) { int mid = (lo + hi) >> 1; if (batch[mid] < g + 1) lo = mid + 1; else hi = mid; }
  int end = lo;

  float acc = 0.f;
  for (int n = beg; n < end; ++n) acc += __half2float(h[(size_t)n * DIM + col]);
  float cnt = fmaxf((float)(end - beg), 1.0f);
  xs[col] = acc / cnt;
  __syncthreads();
  float o = bias[col];
  for (int k = 0; k < DIM; ++k)
    o = fmaf(xs[k], W[(size_t)k * DIM + col], o);
  out[(size_t)g * DIM + col] = fmaxf(o, 0.f);
}

extern "C" void kernel_launch(void* const* d_in, const int* in_sizes, int n_in,
                              void* d_out, int out_size, void* d_ws, size_t ws_size,
                              hipStream_t stream) {
  const float* x    = (const float*)d_in[0];
  const int*   ei   = (const int*)d_in[1];
  const int*   batch= (const int*)d_in[2];
  const float* w0 = (const float*)d_in[3];  const float* b0 = (const float*)d_in[4];
  const float* w1 = (const float*)d_in[5];  const float* b1 = (const float*)d_in[6];
  const float* w2 = (const float*)d_in[7];  const float* b2 = (const float*)d_in[8];
  const float* w3 = (const float*)d_in[9];  const float* b3 = (const float*)d_in[10];
  const float* wp = (const float*)d_in[11]; const float* bp = (const float*)d_in[12];
  float* out = (float*)d_out;

  const int* src = ei;
  const int* dst = ei + N_EDGES;

  // ws layout: xh[50000*64]h | y[50000*128]h | h[50000*128]h
  //          | Wt0[64*128]h | Wt1..3[128*128]h | cnt | fill | part[64] | row_ptr | csr_src
  __half* xh = (__half*)d_ws;
  __half* y  = xh + (size_t)N_NODES * N_FEAT;
  __half* h  = y  + (size_t)N_NODES * DIM;
  __half* Wt0 = h + (size_t)N_NODES * DIM;
  __half* Wt1 = Wt0 + N_FEAT * DIM;
  __half* Wt2 = Wt1 + DIM * DIM;
  __half* Wt3 = Wt2 + DIM * DIM;
  int* cnt     = (int*)(Wt3 + DIM * DIM);
  int* fill    = cnt + N_NODES;
  int* part    = fill + N_NODES;
  int* row_ptr = part + 64;
  int* csr_src = row_ptr + (N_NODES + 1);

  // ---- CSR build ----
  hipMemsetAsync(cnt, 0, (size_t)2 * N_NODES * sizeof(int), stream);
  hist_k<<<(N_EDGES + 255) / 256, 256, 0, stream>>>(dst, cnt);
  scan_part_k <<<NB_SCAN, 256, 0, stream>>>(cnt, part);
  scan_small_k<<<1, 64, 0, stream>>>(part);
  scan_write_k<<<NB_SCAN, 256, 0, stream>>>(cnt, part, row_ptr);
  fill_k<<<(N_EDGES + 255) / 256, 256, 0, stream>>>(src, dst, row_ptr, fill, csr_src);

  // ---- merged prep ----
  {
    int total = XWORK + N_FEAT * DIM + 3 * DIM * DIM;
    prep_k<<<(total + 255) / 256, 256, 0, stream>>>(x, xh, w0, w1, w2, w3,
                                                    Wt0, Wt1, Wt2, Wt3);
  }

  // ---- 4 layers ----
  int ggrid = (N_NODES * 16 + 255) / 256;   // 16 lanes per node
  int mgrid = (N_NODES + 63) / 64;

  mfma_gemm_k<N_FEAT><<<mgrid, 256, 0, stream>>>(xh, Wt0, y, N_NODES);
  gather_relu_k<<<ggrid, 256, 0, stream>>>(y, row_ptr, csr_src, b0, h);

  const __half* Wl[3] = {Wt1, Wt2, Wt3};
  const float*  Bl[3] = {b1, b2, b3};
  for (int l = 0; l < 3; ++l) {
    mfma_gemm_k<DIM><<<mgrid, 256, 0, stream>>>(h, Wl[l], y, N_NODES);
    gather_relu_k<<<ggrid, 256, 0, stream>>>(y, row_ptr, csr_src, Bl[l], h);
  }

  // ---- pool + post-MLP ----
  pool_post_k<<<N_GRAPHS, 128, 0, stream>>>(h, batch, wp, bp, out);
}